// Round 18
// baseline (480.668 us; speedup 1.0000x reference)
//
#include <hip/hip_runtime.h>
#include <math.h>

#define D64 64
#define ES16 16
#define NB5 256

typedef unsigned short u16;
typedef _Float16 half8 __attribute__((ext_vector_type(8)));
typedef __attribute__((ext_vector_type(4))) float f32x4;

// fp16 MFMA pipeline (rounds 10/15/16 verified; absmax 0.0).
// Ledgers closed: k_count plain-int atomics 67us (packed u16 = 70, worse:
// same-word contention; atomic-op-rate bound ~10/cyc device-wide).
// k_fill2 atomic-free via precomputed ranks (round-16).
// Round-18: k_aggr FUSED into k34 (Sin/Sout are node-local; gather writes
// straight to xA LDS rows; gather of block A overlaps MFMA of block B).

__device__ __forceinline__ float sigf(float x){ return 1.0f/(1.0f + __expf(-x)); }
__device__ __forceinline__ float tanhfast(float x){ return 2.0f*sigf(2.0f*x) - 1.0f; }
__device__ __forceinline__ u16 f2h(float f){             // RNE fp32->fp16
  _Float16 h = (_Float16)f;
  u16 r; __builtin_memcpy(&r, &h, 2); return r;
}
__device__ __forceinline__ float h2f(u16 b){
  _Float16 h; __builtin_memcpy(&h, &b, 2); return (float)h;
}
__device__ __forceinline__ float2 up2(unsigned w){       // u32 -> 2 floats
  _Float16 lo, hi;
  u16 a = (u16)(w & 0xFFFF), b = (u16)(w >> 16);
  __builtin_memcpy(&lo, &a, 2); __builtin_memcpy(&hi, &b, 2);
  return make_float2((float)lo, (float)hi);
}

// ---------------- CSR build ----------------
// Plain int counters + per-edge ranks (atomicAdd return; contiguous stores).
__global__ void k_count(const int* __restrict__ u, const int* __restrict__ v,
                        int* __restrict__ cnt, int* __restrict__ rin,
                        int* __restrict__ rout, int N, int E){
  int e = blockIdx.x*256 + threadIdx.x;
  if(e < E){
    rin[e]  = atomicAdd(&cnt[v[e]], 1);
    rout[e] = atomicAdd(&cnt[N + u[e]], 1);
  }
}

__global__ void k_scan1(const int* __restrict__ cnt, int* __restrict__ part, int M){
  __shared__ int sm[256];
  int i = blockIdx.x*256 + threadIdx.x;
  sm[threadIdx.x] = (i < M) ? cnt[i] : 0;
  __syncthreads();
  for(int s = 128; s > 0; s >>= 1){
    if(threadIdx.x < s) sm[threadIdx.x] += sm[threadIdx.x + s];
    __syncthreads();
  }
  if(threadIdx.x == 0) part[blockIdx.x] = sm[0];
}

__global__ void k_scan2(int* __restrict__ part, int nb){
  __shared__ int sm[1024];
  int t = threadIdx.x;
  int orig = (t < nb) ? part[t] : 0;
  sm[t] = orig;
  __syncthreads();
  for(int off = 1; off < 1024; off <<= 1){
    int add = (t >= off) ? sm[t - off] : 0;
    __syncthreads();
    sm[t] += add;
    __syncthreads();
  }
  if(t < nb) part[t] = sm[t] - orig;  // exclusive prefix
}

__global__ void k_scan3(int* __restrict__ cnt, const int* __restrict__ part,
                        int M, int total){
  __shared__ int sm[256];
  int t = threadIdx.x;
  int i = blockIdx.x*256 + t;
  int orig = (i < M) ? cnt[i] : 0;
  sm[t] = orig;
  __syncthreads();
  for(int off = 1; off < 256; off <<= 1){
    int add = (t >= off) ? sm[t - off] : 0;
    __syncthreads();
    sm[t] += add;
    __syncthreads();
  }
  if(i < M) cnt[i] = part[blockIdx.x] + sm[t] - orig;   // exclusive offset
  if(i == 0) cnt[M] = total;
}

// Atomic-free scatter: positions from off[] + precomputed ranks.
__global__ void k_fill2(const int* __restrict__ u, const int* __restrict__ v,
                        const int* __restrict__ off, const int* __restrict__ rin,
                        const int* __restrict__ rout, int* __restrict__ rows,
                        int* __restrict__ srcs, int N, int E){
  int e = blockIdx.x*256 + threadIdx.x;
  if(e < E){
    int uu = u[e], vv = v[e];
    int p = off[vv] + rin[e];
    int q = off[N + uu] + rout[e];
    rows[p] = e; srcs[p] = uu;
    rows[q] = e; srcs[q] = vv;
  }
}

// ---------------- fp32 -> fp16 h conversion (round 0 input) ----------------
__global__ void k_cvt16(const float* __restrict__ src, u16* __restrict__ dst, int total){
  int i = blockIdx.x*256 + threadIdx.x;
  if(i < total) dst[i] = f2h(src[i]);
}

// ---------------- round-constant edge-feature sums ----------------
__global__ void k_einout(const float* __restrict__ ev, const int* __restrict__ off,
                         const int* __restrict__ rows,
                         float* __restrict__ Ein, float* __restrict__ Eout, int N){
  int n = (blockIdx.x*blockDim.x + threadIdx.x) >> 6;
  int lane = threadIdx.x & 63;
  if(n >= N) return;
  int t = lane & 15, s = lane >> 4;
  {
    float a0 = 0.f, a1 = 0.f;
    int p = off[n] + s, p1 = off[n+1];
    for(; p + 4 < p1; p += 8){
      a0 += ev[rows[p]*ES16 + t];
      a1 += ev[rows[p+4]*ES16 + t];
    }
    if(p < p1) a0 += ev[rows[p]*ES16 + t];
    float a = a0 + a1;
    a += __shfl_xor(a, 16, 64);
    a += __shfl_xor(a, 32, 64);
    if(lane < 16) Ein[n*ES16 + lane] = a;
  }
  {
    float b0 = 0.f, b1 = 0.f;
    int p = off[N+n] + s, p1 = off[N+n+1];
    for(; p + 4 < p1; p += 8){
      b0 += ev[rows[p]*ES16 + t];
      b1 += ev[rows[p+4]*ES16 + t];
    }
    if(p < p1) b0 += ev[rows[p]*ES16 + t];
    float b = b0 + b1;
    b += __shfl_xor(b, 16, 64);
    b += __shfl_xor(b, 32, 64);
    if(lane < 16) Eout[n*ES16 + lane] = b;
  }
}

// ---------------- merged weight -> fp16 B-fragment preprocess ----------------
__global__ void k_pre(const float* __restrict__ Wef, const float* __restrict__ bef,
                      const float* __restrict__ Wer, const float* __restrict__ ber,
                      const float* __restrict__ Wih, const float* __restrict__ Whh,
                      const float* __restrict__ bih, const float* __restrict__ bhh,
                      const float* __restrict__ Wfm, const float* __restrict__ Wgm,
                      u16* __restrict__ bA, u16* __restrict__ bB,
                      u16* __restrict__ bC, int R){
  int b = blockIdx.x;
  int lane = threadIdx.x;
  u16 val8[8];
  u16* dst;
  if(b < R*80){
    int r = b / 80, t = b % 80;
    int nt = t / 10, kt = t % 10;
    int j = nt*16 + (lane & 15);
    int ks0 = kt*32 + (lane >> 4)*8;
    const float* wef = Wef + (size_t)r*128*144;
    const float* wer = Wer + (size_t)r*128*144;
    #pragma unroll
    for(int e = 0; e < 8; ++e){
      int ks = ks0 + e;
      float val;
      if(ks < 144)       val = wef[j*144 + ks];
      else if(ks == 144) val = bef[r*128 + j];
      else if(ks < 160)  val = 0.f;
      else if(ks < 304)  val = wer[j*144 + (ks - 160)];
      else if(ks == 304) val = ber[r*128 + j];
      else               val = 0.f;
      val8[e] = f2h(val);
    }
    dst = bA + ((size_t)b*64 + lane)*8;
  } else if(b < R*80 + R*96){
    int bb = b - R*80;
    int r = bb / 96, t = bb % 96;
    int nt = t / 8, kt = t % 8;
    int q = nt*16 + (lane & 15);
    int ks0 = kt*32 + (lane >> 4)*8;
    const float* wih = Wih + (size_t)r*192*128;
    const float* whh = Whh + (size_t)r*192*64;
    #pragma unroll
    for(int e = 0; e < 8; ++e){
      int ks = ks0 + e;
      float val;
      if(ks < 128)       val = wih[q*128 + ks];
      else if(ks == 128) val = bih[r*192 + q];
      else if(ks < 160)  val = 0.f;
      else if(ks < 224)  val = whh[q*64 + (ks - 160)];
      else if(ks == 224) val = bhh[r*192 + q];
      else               val = 0.f;
      val8[e] = f2h(val);
    }
    dst = bB + ((size_t)bb*64 + lane)*8;
  } else {
    int bb = b - R*80 - R*96;
    int nt = bb >> 2, kt = (bb >> 1) & 1, fg = bb & 1;
    int j = nt*16 + (lane & 15);
    int ks0 = kt*32 + (lane >> 4)*8;
    const float* W = fg ? Wgm : Wfm;
    #pragma unroll
    for(int e = 0; e < 8; ++e) val8[e] = f2h(W[j*64 + ks0 + e]);
    dst = bC + ((size_t)bb*64 + lane)*8;
  }
  #pragma unroll
  for(int e = 0; e < 8; ++e) dst[e] = val8[e];
}

// ------- fused gather + node transform + GRU via MFMA (fp16, h16-only) ------
// 512 threads = 8 waves per 64-node tile.
// Phase 0: wave wv gathers Sin/Sout for its 8 nodes (half-wave per direction,
// 16/8/4/1 MLP unroll) straight into xA LDS rows [0:64) / [224:288).
// Phase A: agg = x @ B_A^T (40 mfma/wave). Phase B: GRU gates (48 mfma/wave).
__global__ __launch_bounds__(512) void k34f(
    const u16* __restrict__ h16, const float* __restrict__ Ein,
    const float* __restrict__ Eout, const int* __restrict__ off,
    const int* __restrict__ srcs,
    const u16* __restrict__ bA, const u16* __restrict__ bB,
    u16* __restrict__ h16next, int N){
  __shared__ u16 xA[64][328];   // 320 + pad
  __shared__ u16 x2[64][264];   // 256 + pad
  const int lane = threadIdx.x & 63;
  const int wv   = __builtin_amdgcn_readfirstlane(threadIdx.x >> 6);
  const int base = blockIdx.x * 64;
  const unsigned* hsrc = (const unsigned*)h16;

  // ---- phase 0: per-node gather into LDS ----
  {
    const int half = lane >> 5;      // 0: Sin region [0:64), 1: Sout [224:288)
    const int fl   = lane & 31;      // feature-pair
    const int roff = (half ? 224 : 0) + fl*2;
    for(int ii = 0; ii < 8; ++ii){
      int i = wv*8 + ii;
      int n = base + i; if(n >= N) n = N - 1;
      const int gw = half ? (N + n) : n;
      int p = off[gw], p1 = off[gw+1];
      float sx0 = 0.f, sy0 = 0.f, sx1 = 0.f, sy1 = 0.f;
      for(; p + 16 <= p1; p += 16){
        int s[16]; unsigned w[16];
        #pragma unroll
        for(int j = 0; j < 16; ++j) s[j] = srcs[p + j];
        #pragma unroll
        for(int j = 0; j < 16; ++j) w[j] = hsrc[(size_t)s[j]*32 + fl];
        #pragma unroll
        for(int j = 0; j < 16; j += 4){
          float2 f0 = up2(w[j]), f1 = up2(w[j+1]), f2 = up2(w[j+2]), f3 = up2(w[j+3]);
          sx0 += f0.x + f1.x; sy0 += f0.y + f1.y;
          sx1 += f2.x + f3.x; sy1 += f2.y + f3.y;
        }
      }
      for(; p + 8 <= p1; p += 8){
        int s0 = srcs[p],   s1 = srcs[p+1], s2 = srcs[p+2], s3 = srcs[p+3];
        int s4 = srcs[p+4], s5 = srcs[p+5], s6 = srcs[p+6], s7 = srcs[p+7];
        unsigned w0 = hsrc[(size_t)s0*32 + fl];
        unsigned w1 = hsrc[(size_t)s1*32 + fl];
        unsigned w2 = hsrc[(size_t)s2*32 + fl];
        unsigned w3 = hsrc[(size_t)s3*32 + fl];
        unsigned w4 = hsrc[(size_t)s4*32 + fl];
        unsigned w5 = hsrc[(size_t)s5*32 + fl];
        unsigned w6 = hsrc[(size_t)s6*32 + fl];
        unsigned w7 = hsrc[(size_t)s7*32 + fl];
        float2 f0 = up2(w0), f1 = up2(w1), f2 = up2(w2), f3 = up2(w3);
        float2 f4 = up2(w4), f5 = up2(w5), f6 = up2(w6), f7 = up2(w7);
        sx0 += (f0.x + f1.x) + (f4.x + f5.x);
        sy0 += (f0.y + f1.y) + (f4.y + f5.y);
        sx1 += (f2.x + f3.x) + (f6.x + f7.x);
        sy1 += (f2.y + f3.y) + (f6.y + f7.y);
      }
      for(; p + 4 <= p1; p += 4){
        int s0 = srcs[p], s1 = srcs[p+1], s2 = srcs[p+2], s3 = srcs[p+3];
        unsigned w0 = hsrc[(size_t)s0*32 + fl];
        unsigned w1 = hsrc[(size_t)s1*32 + fl];
        unsigned w2 = hsrc[(size_t)s2*32 + fl];
        unsigned w3 = hsrc[(size_t)s3*32 + fl];
        float2 f0 = up2(w0), f1 = up2(w1), f2 = up2(w2), f3 = up2(w3);
        sx0 += f0.x + f1.x; sy0 += f0.y + f1.y;
        sx1 += f2.x + f3.x; sy1 += f2.y + f3.y;
      }
      for(; p < p1; ++p){
        float2 f0 = up2(hsrc[(size_t)srcs[p]*32 + fl]);
        sx0 += f0.x; sy0 += f0.y;
      }
      unsigned pw = (unsigned)f2h(sx0 + sx1) | ((unsigned)f2h(sy0 + sy1) << 16);
      *(unsigned*)&xA[i][roff] = pw;
    }
  }

  // ---- staging of h / E / fi / fo regions ----
  for(int ii = 0; ii < 8; ++ii){
    int i = wv*8 + ii;
    int n = base + i; if(n >= N) n = N - 1;
    float fi = (float)(off[n+1] - off[n]);
    float fo = (float)(off[N+n+1] - off[N+n]);
    u16 hv16 = h16[(size_t)n*D64 + lane];
    float hv = h2f(hv16);
    xA[i][64 + lane]   = f2h(fi*hv);
    xA[i][160 + lane]  = f2h(fo*hv);
    x2[i][160 + lane]  = hv16;
    if(lane < 16){
      xA[i][128 + lane] = f2h(Ein[(size_t)n*ES16 + lane]);
      xA[i][288 + lane] = f2h(Eout[(size_t)n*ES16 + lane]);
    }
    if(lane == 0){
      xA[i][144] = f2h(fi); xA[i][304] = f2h(fo);
      x2[i][128] = 0x3C00;  x2[i][224] = 0x3C00;   // fp16 1.0
    }
    if(lane >= 1 && lane < 16){ xA[i][144 + lane] = 0; xA[i][304 + lane] = 0; }
    if(lane >= 1 && lane < 32){ x2[i][128 + lane] = 0; x2[i][224 + lane] = 0; }
  }
  __syncthreads();

  // ---- phase A: agg = x @ B_A^T ; wave n-tile = wv ----
  half8 bw[10];
  #pragma unroll
  for(int kt = 0; kt < 10; ++kt)
    bw[kt] = *(const half8*)(bA + ((size_t)(wv*10 + kt)*64 + lane)*8);

  f32x4 accA[4];
  const int arow = lane & 15;
  const int akof = (lane >> 4) * 8;
  #pragma unroll
  for(int m = 0; m < 4; ++m){
    f32x4 a = {0.f, 0.f, 0.f, 0.f};
    #pragma unroll
    for(int kt = 0; kt < 10; ++kt){
      half8 av = *(const half8*)&xA[m*16 + arow][kt*32 + akof];
      a = __builtin_amdgcn_mfma_f32_16x16x32_f16(av, bw[kt], a, 0, 0, 0);
    }
    accA[m] = a;
  }

  // ---- agg (fp16) -> x2[:, jb..jb+15]; C/D: col=lane&15, row=(lane>>4)*4+reg ----
  const int jb = wv * 16;
  #pragma unroll
  for(int m = 0; m < 4; ++m){
    #pragma unroll
    for(int reg = 0; reg < 4; ++reg){
      int nl = m*16 + (lane >> 4)*4 + reg;
      x2[nl][jb + (lane & 15)] = f2h(accA[m][reg]);
    }
  }
  __syncthreads();

  // ---- phase B: gates = x2 @ B_B^T ; 2 units/wave ----
  #pragma unroll
  for(int uu = 0; uu < 2; ++uu){
    const int unit = wv*2 + uu;
    const int mt  = unit >> 2;
    const int tri = unit & 3;
    f32x4 aR  = {0.f,0.f,0.f,0.f};
    f32x4 aZ  = {0.f,0.f,0.f,0.f};
    f32x4 aNi = {0.f,0.f,0.f,0.f};
    f32x4 aNh = {0.f,0.f,0.f,0.f};
    #pragma unroll
    for(int kt = 0; kt < 8; ++kt){
      half8 av = *(const half8*)&x2[mt*16 + arow][kt*32 + akof];
      half8 bR = *(const half8*)(bB + ((size_t)((tri    )*8 + kt)*64 + lane)*8);
      half8 bZ = *(const half8*)(bB + ((size_t)((tri + 4)*8 + kt)*64 + lane)*8);
      half8 bN = *(const half8*)(bB + ((size_t)((tri + 8)*8 + kt)*64 + lane)*8);
      aR = __builtin_amdgcn_mfma_f32_16x16x32_f16(av, bR, aR, 0, 0, 0);
      aZ = __builtin_amdgcn_mfma_f32_16x16x32_f16(av, bZ, aZ, 0, 0, 0);
      if(kt < 5) aNi = __builtin_amdgcn_mfma_f32_16x16x32_f16(av, bN, aNi, 0, 0, 0);
      else       aNh = __builtin_amdgcn_mfma_f32_16x16x32_f16(av, bN, aNh, 0, 0, 0);
    }
    const int q = tri*16 + (lane & 15);
    #pragma unroll
    for(int reg = 0; reg < 4; ++reg){
      int node = base + mt*16 + (lane >> 4)*4 + reg;
      float r  = sigf(aR[reg]);
      float z  = sigf(aZ[reg]);
      float nn = tanhfast(aNi[reg] + r*aNh[reg]);
      if(node < N){
        float hq = h2f(h16[(size_t)node*D64 + q]);
        h16next[(size_t)node*D64 + q] = f2h((1.f - z)*nn + z*hq);
      }
    }
  }
}

// ---------------- gated readout via MFMA ----------------
__global__ __launch_bounds__(512) void k5m(
    const u16* __restrict__ h16, const u16* __restrict__ bC,
    const float* __restrict__ bfm, const float* __restrict__ bgm,
    float* __restrict__ partials, int N, int nT){
  __shared__ u16 xh[64][72];   // 64 fp16 + pad -> 144B stride (9*16)
  const int lane = threadIdx.x & 63;
  const int wv   = __builtin_amdgcn_readfirstlane(threadIdx.x >> 6);
  const int arow = lane & 15;
  const int akof = (lane >> 4) * 8;
  half8 bF[2], bG[2];
  #pragma unroll
  for(int kt = 0; kt < 2; ++kt){
    bF[kt] = *(const half8*)(bC + ((size_t)(wv*4 + kt*2 + 0)*64 + lane)*8);
    bG[kt] = *(const half8*)(bC + ((size_t)(wv*4 + kt*2 + 1)*64 + lane)*8);
  }
  const float fb = bfm[wv*16 + arow];
  const float gb = bgm[wv*16 + arow];
  float acc = 0.f;
  for(int tile = blockIdx.x; tile < nT; tile += NB5){
    const int base = tile * 64;
    __syncthreads();
    for(int ii = 0; ii < 8; ++ii){
      int i = wv*8 + ii;
      int n = base + i;
      xh[i][lane] = (n < N) ? h16[(size_t)n*D64 + lane] : (u16)0;
    }
    __syncthreads();
    #pragma unroll
    for(int m = 0; m < 4; ++m){
      f32x4 F = {0.f,0.f,0.f,0.f};
      f32x4 G = {0.f,0.f,0.f,0.f};
      #pragma unroll
      for(int kt = 0; kt < 2; ++kt){
        half8 av = *(const half8*)&xh[m*16 + arow][kt*32 + akof];
        F = __builtin_amdgcn_mfma_f32_16x16x32_f16(av, bF[kt], F, 0, 0, 0);
        G = __builtin_amdgcn_mfma_f32_16x16x32_f16(av, bG[kt], G, 0, 0, 0);
      }
      #pragma unroll
      for(int reg = 0; reg < 4; ++reg){
        int node = base + m*16 + (lane >> 4)*4 + reg;
        if(node < N)
          acc += (F[reg] + fb) * sigf(G[reg] + gb);
      }
    }
  }
  acc += __shfl_xor(acc, 16, 64);
  acc += __shfl_xor(acc, 32, 64);
  if(lane < 16) partials[blockIdx.x*128 + wv*16 + lane] = acc;
}

__global__ void k6_dec(const float* __restrict__ partials, int nb,
                       const u16* __restrict__ h16,
                       const float* __restrict__ Wdec, const float* __restrict__ bdec,
                       const int* __restrict__ tgt, float* __restrict__ out){
  __shared__ float sm[256];
  int t = threadIdx.x;
  float v = 0.f;
  if(t < 128){
    float s0 = 0.f, s1 = 0.f, s2 = 0.f, s3 = 0.f;
    for(int b = 0; b + 4 <= nb; b += 4){
      s0 += partials[(b+0)*128 + t];
      s1 += partials[(b+1)*128 + t];
      s2 += partials[(b+2)*128 + t];
      s3 += partials[(b+3)*128 + t];
    }
    v = ((s0 + s1) + (s2 + s3)) * Wdec[t];
  } else if(t < 192){
    v = h2f(h16[(size_t)tgt[0]*D64 + (t - 128)]) * Wdec[t];
  }
  sm[t] = v;
  __syncthreads();
  for(int s = 128; s > 0; s >>= 1){
    if(t < s) sm[t] += sm[t + s];
    __syncthreads();
  }
  if(t == 0) out[0] = sm[0] + bdec[0];
}

extern "C" void kernel_launch(void* const* d_in, const int* in_sizes, int n_in,
                              void* d_out, int out_size, void* d_ws, size_t ws_size,
                              hipStream_t stream){
  const float* nodev = (const float*)d_in[0];
  const float* ev    = (const float*)d_in[1];
  const float* Wef   = (const float*)d_in[2];
  const float* bef   = (const float*)d_in[3];
  const float* Wer   = (const float*)d_in[4];
  const float* ber   = (const float*)d_in[5];
  const float* Wih   = (const float*)d_in[6];
  const float* Whh   = (const float*)d_in[7];
  const float* bih   = (const float*)d_in[8];
  const float* bhh   = (const float*)d_in[9];
  const float* Wfm   = (const float*)d_in[10];
  const float* bfm   = (const float*)d_in[11];
  const float* Wgm   = (const float*)d_in[12];
  const float* bgm   = (const float*)d_in[13];
  const float* Wdec  = (const float*)d_in[14];
  const float* bdec  = (const float*)d_in[15];
  const int* uidx    = (const int*)d_in[16];
  const int* vidx    = (const int*)d_in[17];
  const int* tgt     = (const int*)d_in[18];

  const int N = in_sizes[0] / 64;
  const int E = in_sizes[16];
  const int R = in_sizes[2] / (128*144);

  char* w = (char*)d_ws;
  auto alloc = [&](size_t bytes) -> void* {
    void* p = (void*)w;
    w += (bytes + 255) & ~(size_t)255;
    return p;
  };
  int* off       = (int*)alloc(((size_t)2*N + 1) * 4);
  int* rin       = (int*)alloc((size_t)E * 4);
  int* rout      = (int*)alloc((size_t)E * 4);
  int* rows      = (int*)alloc((size_t)2*E * 4);
  int* srcs      = (int*)alloc((size_t)2*E * 4);
  int* part      = (int*)alloc(4096 * 4);
  float* Ein     = (float*)alloc((size_t)N*16*4);
  float* Eout    = (float*)alloc((size_t)N*16*4);
  u16* g0        = (u16*)alloc((size_t)N*64*2);        // fp16 h buffers
  u16* gA        = (u16*)alloc((size_t)N*64*2);
  u16* gB        = (u16*)alloc((size_t)N*64*2);
  u16* bA        = (u16*)alloc((size_t)R*80*64*8*2);
  u16* bB        = (u16*)alloc((size_t)R*96*64*8*2);
  u16* bC        = (u16*)alloc((size_t)32*64*8*2);
  float* partial = (float*)alloc((size_t)NB5*128*4);

  hipMemsetAsync(off, 0, ((size_t)2*N+1)*4, stream);

  int eb = (E + 255)/256;
  k_count<<<eb, 256, 0, stream>>>(uidx, vidx, off, rin, rout, N, E);
  int M = 2*N;
  int nb = (M + 255)/256;
  k_scan1<<<nb, 256, 0, stream>>>(off, part, M);
  k_scan2<<<1, 1024, 0, stream>>>(part, nb);
  k_scan3<<<nb, 256, 0, stream>>>(off, part, M, 2*E);
  k_fill2<<<eb, 256, 0, stream>>>(uidx, vidx, off, rin, rout, rows, srcs, N, E);
  int wb = (N + 3)/4;
  k_einout<<<wb, 256, 0, stream>>>(ev, off, rows, Ein, Eout, N);
  k_cvt16<<<(N*64 + 255)/256, 256, 0, stream>>>(nodev, g0, N*64);

  // one-time fp16 B-fragment builds (merged)
  k_pre<<<R*80 + R*96 + 32, 64, 0, stream>>>(Wef, bef, Wer, ber, Wih, Whh,
                                             bih, bhh, Wfm, Wgm, bA, bB, bC, R);

  int nT = (N + 63)/64;
  const u16* g16cur = g0;
  u16* gbufs[2] = {gA, gB};
  for(int r = 0; r < R; ++r){
    u16* gn = gbufs[r & 1];
    k34f<<<nT, 512, 0, stream>>>(g16cur, Ein, Eout, off, srcs,
                                 bA + (size_t)r*80*64*8,
                                 bB + (size_t)r*96*64*8,
                                 gn, N);
    g16cur = gn;
  }
  k5m<<<NB5, 512, 0, stream>>>(g16cur, bC, bfm, bgm, partial, N, nT);
  k6_dec<<<1, 256, 0, stream>>>(partial, NB5, g16cur, Wdec, bdec, tgt, (float*)d_out);
}

// Round 19
// 418.700 us; speedup vs baseline: 1.1480x; 1.1480x over previous
//
#include <hip/hip_runtime.h>
#include <math.h>

#define D64 64
#define ES16 16
#define NB5 256

typedef unsigned short u16;
typedef _Float16 half8 __attribute__((ext_vector_type(8)));
typedef __attribute__((ext_vector_type(4))) float f32x4;

// fp16 MFMA pipeline — BEST CONFIG (round-16 measured 421us), all ledgers closed:
// k_count: plain-int atomics+ranks (67us; packed-u16 = 70 worse; atomic-op-rate
//   bound ~10/cyc device-wide).
// k_fill2: atomic-free scatter via precomputed ranks (plain 4B stores; int2 and
//   nontemporal variants both regressed).
// k_aggr: standalone, wave/node, half-wave/direction, fp16 gathers, 16/8/4/1
//   unroll (gather-request-rate bound; round-18 fusion into k34 regressed:
//   282us fused vs 210us separate — lost inter-node MLP + LDS conflicts).
// k34_mfma: fp16 MFMA, h16-only state (absmax 0.0 => ample headroom).

__device__ __forceinline__ float sigf(float x){ return 1.0f/(1.0f + __expf(-x)); }
__device__ __forceinline__ float tanhfast(float x){ return 2.0f*sigf(2.0f*x) - 1.0f; }
__device__ __forceinline__ u16 f2h(float f){             // RNE fp32->fp16
  _Float16 h = (_Float16)f;
  u16 r; __builtin_memcpy(&r, &h, 2); return r;
}
__device__ __forceinline__ float h2f(u16 b){
  _Float16 h; __builtin_memcpy(&h, &b, 2); return (float)h;
}
__device__ __forceinline__ float2 up2(unsigned w){       // u32 -> 2 floats
  _Float16 lo, hi;
  u16 a = (u16)(w & 0xFFFF), b = (u16)(w >> 16);
  __builtin_memcpy(&lo, &a, 2); __builtin_memcpy(&hi, &b, 2);
  return make_float2((float)lo, (float)hi);
}

// ---------------- CSR build ----------------
__global__ void k_count(const int* __restrict__ u, const int* __restrict__ v,
                        int* __restrict__ cnt, int* __restrict__ rin,
                        int* __restrict__ rout, int N, int E){
  int e = blockIdx.x*256 + threadIdx.x;
  if(e < E){
    rin[e]  = atomicAdd(&cnt[v[e]], 1);
    rout[e] = atomicAdd(&cnt[N + u[e]], 1);
  }
}

__global__ void k_scan1(const int* __restrict__ cnt, int* __restrict__ part, int M){
  __shared__ int sm[256];
  int i = blockIdx.x*256 + threadIdx.x;
  sm[threadIdx.x] = (i < M) ? cnt[i] : 0;
  __syncthreads();
  for(int s = 128; s > 0; s >>= 1){
    if(threadIdx.x < s) sm[threadIdx.x] += sm[threadIdx.x + s];
    __syncthreads();
  }
  if(threadIdx.x == 0) part[blockIdx.x] = sm[0];
}

__global__ void k_scan2(int* __restrict__ part, int nb){
  __shared__ int sm[1024];
  int t = threadIdx.x;
  int orig = (t < nb) ? part[t] : 0;
  sm[t] = orig;
  __syncthreads();
  for(int off = 1; off < 1024; off <<= 1){
    int add = (t >= off) ? sm[t - off] : 0;
    __syncthreads();
    sm[t] += add;
    __syncthreads();
  }
  if(t < nb) part[t] = sm[t] - orig;  // exclusive prefix
}

__global__ void k_scan3(int* __restrict__ cnt, const int* __restrict__ part,
                        int M, int total){
  __shared__ int sm[256];
  int t = threadIdx.x;
  int i = blockIdx.x*256 + t;
  int orig = (i < M) ? cnt[i] : 0;
  sm[t] = orig;
  __syncthreads();
  for(int off = 1; off < 256; off <<= 1){
    int add = (t >= off) ? sm[t - off] : 0;
    __syncthreads();
    sm[t] += add;
    __syncthreads();
  }
  if(i < M) cnt[i] = part[blockIdx.x] + sm[t] - orig;   // exclusive offset
  if(i == 0) cnt[M] = total;
}

// Atomic-free scatter: positions from off[] + precomputed ranks.
__global__ void k_fill2(const int* __restrict__ u, const int* __restrict__ v,
                        const int* __restrict__ off, const int* __restrict__ rin,
                        const int* __restrict__ rout, int* __restrict__ rows,
                        int* __restrict__ srcs, int N, int E){
  int e = blockIdx.x*256 + threadIdx.x;
  if(e < E){
    int uu = u[e], vv = v[e];
    int p = off[vv] + rin[e];
    int q = off[N + uu] + rout[e];
    rows[p] = e; srcs[p] = uu;
    rows[q] = e; srcs[q] = vv;
  }
}

// ---------------- fp32 -> fp16 h conversion (round 0 input) ----------------
__global__ void k_cvt16(const float* __restrict__ src, u16* __restrict__ dst, int total){
  int i = blockIdx.x*256 + threadIdx.x;
  if(i < total) dst[i] = f2h(src[i]);
}

// ---------------- round-constant edge-feature sums ----------------
__global__ void k_einout(const float* __restrict__ ev, const int* __restrict__ off,
                         const int* __restrict__ rows,
                         float* __restrict__ Ein, float* __restrict__ Eout, int N){
  int n = (blockIdx.x*blockDim.x + threadIdx.x) >> 6;
  int lane = threadIdx.x & 63;
  if(n >= N) return;
  int t = lane & 15, s = lane >> 4;
  {
    float a0 = 0.f, a1 = 0.f;
    int p = off[n] + s, p1 = off[n+1];
    for(; p + 4 < p1; p += 8){
      a0 += ev[rows[p]*ES16 + t];
      a1 += ev[rows[p+4]*ES16 + t];
    }
    if(p < p1) a0 += ev[rows[p]*ES16 + t];
    float a = a0 + a1;
    a += __shfl_xor(a, 16, 64);
    a += __shfl_xor(a, 32, 64);
    if(lane < 16) Ein[n*ES16 + lane] = a;
  }
  {
    float b0 = 0.f, b1 = 0.f;
    int p = off[N+n] + s, p1 = off[N+n+1];
    for(; p + 4 < p1; p += 8){
      b0 += ev[rows[p]*ES16 + t];
      b1 += ev[rows[p+4]*ES16 + t];
    }
    if(p < p1) b0 += ev[rows[p]*ES16 + t];
    float b = b0 + b1;
    b += __shfl_xor(b, 16, 64);
    b += __shfl_xor(b, 32, 64);
    if(lane < 16) Eout[n*ES16 + lane] = b;
  }
}

// ---------------- per-round sparse aggregation ----------------
// One wave per NODE; lanes 0..31 = in, lanes 32..63 = out. 16/8/4/1 unroll.
__global__ void k_aggr(const u16* __restrict__ h16, const int* __restrict__ off,
                       const int* __restrict__ srcs,
                       u16* __restrict__ Sin16, u16* __restrict__ Sout16, int N){
  int n = (blockIdx.x*blockDim.x + threadIdx.x) >> 6;
  int lane = threadIdx.x & 63;
  if(n >= N) return;
  const int half = lane >> 5;          // 0: Sin, 1: Sout
  const int fl   = lane & 31;          // feature-pair index
  const int gw   = half ? (N + n) : n;
  int p  = off[gw], p1 = off[gw+1];
  const unsigned* hsrc = (const unsigned*)h16;
  float sx0 = 0.f, sy0 = 0.f, sx1 = 0.f, sy1 = 0.f;
  for(; p + 16 <= p1; p += 16){
    int s[16]; unsigned w[16];
    #pragma unroll
    for(int j = 0; j < 16; ++j) s[j] = srcs[p + j];
    #pragma unroll
    for(int j = 0; j < 16; ++j) w[j] = hsrc[(size_t)s[j]*32 + fl];
    #pragma unroll
    for(int j = 0; j < 16; j += 4){
      float2 f0 = up2(w[j]), f1 = up2(w[j+1]), f2 = up2(w[j+2]), f3 = up2(w[j+3]);
      sx0 += f0.x + f1.x; sy0 += f0.y + f1.y;
      sx1 += f2.x + f3.x; sy1 += f2.y + f3.y;
    }
  }
  for(; p + 8 <= p1; p += 8){
    int s0 = srcs[p],   s1 = srcs[p+1], s2 = srcs[p+2], s3 = srcs[p+3];
    int s4 = srcs[p+4], s5 = srcs[p+5], s6 = srcs[p+6], s7 = srcs[p+7];
    unsigned w0 = hsrc[(size_t)s0*32 + fl];
    unsigned w1 = hsrc[(size_t)s1*32 + fl];
    unsigned w2 = hsrc[(size_t)s2*32 + fl];
    unsigned w3 = hsrc[(size_t)s3*32 + fl];
    unsigned w4 = hsrc[(size_t)s4*32 + fl];
    unsigned w5 = hsrc[(size_t)s5*32 + fl];
    unsigned w6 = hsrc[(size_t)s6*32 + fl];
    unsigned w7 = hsrc[(size_t)s7*32 + fl];
    float2 f0 = up2(w0), f1 = up2(w1), f2 = up2(w2), f3 = up2(w3);
    float2 f4 = up2(w4), f5 = up2(w5), f6 = up2(w6), f7 = up2(w7);
    sx0 += (f0.x + f1.x) + (f4.x + f5.x);
    sy0 += (f0.y + f1.y) + (f4.y + f5.y);
    sx1 += (f2.x + f3.x) + (f6.x + f7.x);
    sy1 += (f2.y + f3.y) + (f6.y + f7.y);
  }
  for(; p + 4 <= p1; p += 4){
    int s0 = srcs[p], s1 = srcs[p+1], s2 = srcs[p+2], s3 = srcs[p+3];
    unsigned w0 = hsrc[(size_t)s0*32 + fl];
    unsigned w1 = hsrc[(size_t)s1*32 + fl];
    unsigned w2 = hsrc[(size_t)s2*32 + fl];
    unsigned w3 = hsrc[(size_t)s3*32 + fl];
    float2 f0 = up2(w0), f1 = up2(w1), f2 = up2(w2), f3 = up2(w3);
    sx0 += f0.x + f1.x; sy0 += f0.y + f1.y;
    sx1 += f2.x + f3.x; sy1 += f2.y + f3.y;
  }
  for(; p < p1; ++p){
    float2 f0 = up2(hsrc[(size_t)srcs[p]*32 + fl]);
    sx0 += f0.x; sy0 += f0.y;
  }
  unsigned pw = (unsigned)f2h(sx0 + sx1) | ((unsigned)f2h(sy0 + sy1) << 16);
  unsigned* dst = half ? (unsigned*)Sout16 : (unsigned*)Sin16;
  dst[(size_t)n*32 + fl] = pw;
}

// ---------------- merged weight -> fp16 B-fragment preprocess ----------------
__global__ void k_pre(const float* __restrict__ Wef, const float* __restrict__ bef,
                      const float* __restrict__ Wer, const float* __restrict__ ber,
                      const float* __restrict__ Wih, const float* __restrict__ Whh,
                      const float* __restrict__ bih, const float* __restrict__ bhh,
                      const float* __restrict__ Wfm, const float* __restrict__ Wgm,
                      u16* __restrict__ bA, u16* __restrict__ bB,
                      u16* __restrict__ bC, int R){
  int b = blockIdx.x;
  int lane = threadIdx.x;
  u16 val8[8];
  u16* dst;
  if(b < R*80){
    int r = b / 80, t = b % 80;
    int nt = t / 10, kt = t % 10;
    int j = nt*16 + (lane & 15);
    int ks0 = kt*32 + (lane >> 4)*8;
    const float* wef = Wef + (size_t)r*128*144;
    const float* wer = Wer + (size_t)r*128*144;
    #pragma unroll
    for(int e = 0; e < 8; ++e){
      int ks = ks0 + e;
      float val;
      if(ks < 144)       val = wef[j*144 + ks];
      else if(ks == 144) val = bef[r*128 + j];
      else if(ks < 160)  val = 0.f;
      else if(ks < 304)  val = wer[j*144 + (ks - 160)];
      else if(ks == 304) val = ber[r*128 + j];
      else               val = 0.f;
      val8[e] = f2h(val);
    }
    dst = bA + ((size_t)b*64 + lane)*8;
  } else if(b < R*80 + R*96){
    int bb = b - R*80;
    int r = bb / 96, t = bb % 96;
    int nt = t / 8, kt = t % 8;
    int q = nt*16 + (lane & 15);
    int ks0 = kt*32 + (lane >> 4)*8;
    const float* wih = Wih + (size_t)r*192*128;
    const float* whh = Whh + (size_t)r*192*64;
    #pragma unroll
    for(int e = 0; e < 8; ++e){
      int ks = ks0 + e;
      float val;
      if(ks < 128)       val = wih[q*128 + ks];
      else if(ks == 128) val = bih[r*192 + q];
      else if(ks < 160)  val = 0.f;
      else if(ks < 224)  val = whh[q*64 + (ks - 160)];
      else if(ks == 224) val = bhh[r*192 + q];
      else               val = 0.f;
      val8[e] = f2h(val);
    }
    dst = bB + ((size_t)bb*64 + lane)*8;
  } else {
    int bb = b - R*80 - R*96;
    int nt = bb >> 2, kt = (bb >> 1) & 1, fg = bb & 1;
    int j = nt*16 + (lane & 15);
    int ks0 = kt*32 + (lane >> 4)*8;
    const float* W = fg ? Wgm : Wfm;
    #pragma unroll
    for(int e = 0; e < 8; ++e) val8[e] = f2h(W[j*64 + ks0 + e]);
    dst = bC + ((size_t)bb*64 + lane)*8;
  }
  #pragma unroll
  for(int e = 0; e < 8; ++e) dst[e] = val8[e];
}

// ---------------- fused node transform + GRU via MFMA (fp16, h16-only) ------
__global__ __launch_bounds__(512) void k34_mfma(
    const u16* __restrict__ h16, const u16* __restrict__ Sin16,
    const u16* __restrict__ Sout16, const float* __restrict__ Ein,
    const float* __restrict__ Eout, const int* __restrict__ off,
    const u16* __restrict__ bA, const u16* __restrict__ bB,
    u16* __restrict__ h16next, int N){
  __shared__ u16 xA[64][328];   // 320 + pad
  __shared__ u16 x2[64][264];   // 256 + pad
  const int lane = threadIdx.x & 63;
  const int wv   = __builtin_amdgcn_readfirstlane(threadIdx.x >> 6);
  const int base = blockIdx.x * 64;

  // ---- staging (all-fp16 inputs) ----
  for(int ii = 0; ii < 8; ++ii){
    int i = wv*8 + ii;
    int n = base + i; if(n >= N) n = N - 1;
    float fi = (float)(off[n+1] - off[n]);
    float fo = (float)(off[N+n+1] - off[N+n]);
    u16 hv16 = h16[(size_t)n*D64 + lane];
    float hv = h2f(hv16);
    xA[i][lane]        = Sin16[(size_t)n*D64 + lane];
    xA[i][64 + lane]   = f2h(fi*hv);
    xA[i][160 + lane]  = f2h(fo*hv);
    xA[i][224 + lane]  = Sout16[(size_t)n*D64 + lane];
    x2[i][160 + lane]  = hv16;
    if(lane < 16){
      xA[i][128 + lane] = f2h(Ein[(size_t)n*ES16 + lane]);
      xA[i][288 + lane] = f2h(Eout[(size_t)n*ES16 + lane]);
    }
    if(lane == 0){
      xA[i][144] = f2h(fi); xA[i][304] = f2h(fo);
      x2[i][128] = 0x3C00;  x2[i][224] = 0x3C00;   // fp16 1.0
    }
    if(lane >= 1 && lane < 16){ xA[i][144 + lane] = 0; xA[i][304 + lane] = 0; }
    if(lane >= 1 && lane < 32){ x2[i][128 + lane] = 0; x2[i][224 + lane] = 0; }
  }
  __syncthreads();

  // ---- phase A: agg = x @ B_A^T ; wave n-tile = wv ----
  half8 bw[10];
  #pragma unroll
  for(int kt = 0; kt < 10; ++kt)
    bw[kt] = *(const half8*)(bA + ((size_t)(wv*10 + kt)*64 + lane)*8);

  f32x4 accA[4];
  const int arow = lane & 15;
  const int akof = (lane >> 4) * 8;
  #pragma unroll
  for(int m = 0; m < 4; ++m){
    f32x4 a = {0.f, 0.f, 0.f, 0.f};
    #pragma unroll
    for(int kt = 0; kt < 10; ++kt){
      half8 av = *(const half8*)&xA[m*16 + arow][kt*32 + akof];
      a = __builtin_amdgcn_mfma_f32_16x16x32_f16(av, bw[kt], a, 0, 0, 0);
    }
    accA[m] = a;
  }

  // ---- agg (fp16) -> x2[:, jb..jb+15]; C/D: col=lane&15, row=(lane>>4)*4+reg ----
  const int jb = wv * 16;
  #pragma unroll
  for(int m = 0; m < 4; ++m){
    #pragma unroll
    for(int reg = 0; reg < 4; ++reg){
      int nl = m*16 + (lane >> 4)*4 + reg;
      x2[nl][jb + (lane & 15)] = f2h(accA[m][reg]);
    }
  }
  __syncthreads();

  // ---- phase B: gates = x2 @ B_B^T ; 2 units/wave ----
  #pragma unroll
  for(int uu = 0; uu < 2; ++uu){
    const int unit = wv*2 + uu;
    const int mt  = unit >> 2;
    const int tri = unit & 3;
    f32x4 aR  = {0.f,0.f,0.f,0.f};
    f32x4 aZ  = {0.f,0.f,0.f,0.f};
    f32x4 aNi = {0.f,0.f,0.f,0.f};
    f32x4 aNh = {0.f,0.f,0.f,0.f};
    #pragma unroll
    for(int kt = 0; kt < 8; ++kt){
      half8 av = *(const half8*)&x2[mt*16 + arow][kt*32 + akof];
      half8 bR = *(const half8*)(bB + ((size_t)((tri    )*8 + kt)*64 + lane)*8);
      half8 bZ = *(const half8*)(bB + ((size_t)((tri + 4)*8 + kt)*64 + lane)*8);
      half8 bN = *(const half8*)(bB + ((size_t)((tri + 8)*8 + kt)*64 + lane)*8);
      aR = __builtin_amdgcn_mfma_f32_16x16x32_f16(av, bR, aR, 0, 0, 0);
      aZ = __builtin_amdgcn_mfma_f32_16x16x32_f16(av, bZ, aZ, 0, 0, 0);
      if(kt < 5) aNi = __builtin_amdgcn_mfma_f32_16x16x32_f16(av, bN, aNi, 0, 0, 0);
      else       aNh = __builtin_amdgcn_mfma_f32_16x16x32_f16(av, bN, aNh, 0, 0, 0);
    }
    const int q = tri*16 + (lane & 15);
    #pragma unroll
    for(int reg = 0; reg < 4; ++reg){
      int node = base + mt*16 + (lane >> 4)*4 + reg;
      float r  = sigf(aR[reg]);
      float z  = sigf(aZ[reg]);
      float nn = tanhfast(aNi[reg] + r*aNh[reg]);
      if(node < N){
        float hq = h2f(h16[(size_t)node*D64 + q]);
        h16next[(size_t)node*D64 + q] = f2h((1.f - z)*nn + z*hq);
      }
    }
  }
}

// ---------------- gated readout via MFMA ----------------
__global__ __launch_bounds__(512) void k5m(
    const u16* __restrict__ h16, const u16* __restrict__ bC,
    const float* __restrict__ bfm, const float* __restrict__ bgm,
    float* __restrict__ partials, int N, int nT){
  __shared__ u16 xh[64][72];   // 64 fp16 + pad -> 144B stride (9*16)
  const int lane = threadIdx.x & 63;
  const int wv   = __builtin_amdgcn_readfirstlane(threadIdx.x >> 6);
  const int arow = lane & 15;
  const int akof = (lane >> 4) * 8;
  half8 bF[2], bG[2];
  #pragma unroll
  for(int kt = 0; kt < 2; ++kt){
    bF[kt] = *(const half8*)(bC + ((size_t)(wv*4 + kt*2 + 0)*64 + lane)*8);
    bG[kt] = *(const half8*)(bC + ((size_t)(wv*4 + kt*2 + 1)*64 + lane)*8);
  }
  const float fb = bfm[wv*16 + arow];
  const float gb = bgm[wv*16 + arow];
  float acc = 0.f;
  for(int tile = blockIdx.x; tile < nT; tile += NB5){
    const int base = tile * 64;
    __syncthreads();
    for(int ii = 0; ii < 8; ++ii){
      int i = wv*8 + ii;
      int n = base + i;
      xh[i][lane] = (n < N) ? h16[(size_t)n*D64 + lane] : (u16)0;
    }
    __syncthreads();
    #pragma unroll
    for(int m = 0; m < 4; ++m){
      f32x4 F = {0.f,0.f,0.f,0.f};
      f32x4 G = {0.f,0.f,0.f,0.f};
      #pragma unroll
      for(int kt = 0; kt < 2; ++kt){
        half8 av = *(const half8*)&xh[m*16 + arow][kt*32 + akof];
        F = __builtin_amdgcn_mfma_f32_16x16x32_f16(av, bF[kt], F, 0, 0, 0);
        G = __builtin_amdgcn_mfma_f32_16x16x32_f16(av, bG[kt], G, 0, 0, 0);
      }
      #pragma unroll
      for(int reg = 0; reg < 4; ++reg){
        int node = base + m*16 + (lane >> 4)*4 + reg;
        if(node < N)
          acc += (F[reg] + fb) * sigf(G[reg] + gb);
      }
    }
  }
  acc += __shfl_xor(acc, 16, 64);
  acc += __shfl_xor(acc, 32, 64);
  if(lane < 16) partials[blockIdx.x*128 + wv*16 + lane] = acc;
}

__global__ void k6_dec(const float* __restrict__ partials, int nb,
                       const u16* __restrict__ h16,
                       const float* __restrict__ Wdec, const float* __restrict__ bdec,
                       const int* __restrict__ tgt, float* __restrict__ out){
  __shared__ float sm[256];
  int t = threadIdx.x;
  float v = 0.f;
  if(t < 128){
    float s0 = 0.f, s1 = 0.f, s2 = 0.f, s3 = 0.f;
    for(int b = 0; b + 4 <= nb; b += 4){
      s0 += partials[(b+0)*128 + t];
      s1 += partials[(b+1)*128 + t];
      s2 += partials[(b+2)*128 + t];
      s3 += partials[(b+3)*128 + t];
    }
    v = ((s0 + s1) + (s2 + s3)) * Wdec[t];
  } else if(t < 192){
    v = h2f(h16[(size_t)tgt[0]*D64 + (t - 128)]) * Wdec[t];
  }
  sm[t] = v;
  __syncthreads();
  for(int s = 128; s > 0; s >>= 1){
    if(t < s) sm[t] += sm[t + s];
    __syncthreads();
  }
  if(t == 0) out[0] = sm[0] + bdec[0];
}

extern "C" void kernel_launch(void* const* d_in, const int* in_sizes, int n_in,
                              void* d_out, int out_size, void* d_ws, size_t ws_size,
                              hipStream_t stream){
  const float* nodev = (const float*)d_in[0];
  const float* ev    = (const float*)d_in[1];
  const float* Wef   = (const float*)d_in[2];
  const float* bef   = (const float*)d_in[3];
  const float* Wer   = (const float*)d_in[4];
  const float* ber   = (const float*)d_in[5];
  const float* Wih   = (const float*)d_in[6];
  const float* Whh   = (const float*)d_in[7];
  const float* bih   = (const float*)d_in[8];
  const float* bhh   = (const float*)d_in[9];
  const float* Wfm   = (const float*)d_in[10];
  const float* bfm   = (const float*)d_in[11];
  const float* Wgm   = (const float*)d_in[12];
  const float* bgm   = (const float*)d_in[13];
  const float* Wdec  = (const float*)d_in[14];
  const float* bdec  = (const float*)d_in[15];
  const int* uidx    = (const int*)d_in[16];
  const int* vidx    = (const int*)d_in[17];
  const int* tgt     = (const int*)d_in[18];

  const int N = in_sizes[0] / 64;
  const int E = in_sizes[16];
  const int R = in_sizes[2] / (128*144);

  char* w = (char*)d_ws;
  auto alloc = [&](size_t bytes) -> void* {
    void* p = (void*)w;
    w += (bytes + 255) & ~(size_t)255;
    return p;
  };
  int* off       = (int*)alloc(((size_t)2*N + 1) * 4);
  int* rin       = (int*)alloc((size_t)E * 4);
  int* rout      = (int*)alloc((size_t)E * 4);
  int* rows      = (int*)alloc((size_t)2*E * 4);
  int* srcs      = (int*)alloc((size_t)2*E * 4);
  int* part      = (int*)alloc(4096 * 4);
  float* Ein     = (float*)alloc((size_t)N*16*4);
  float* Eout    = (float*)alloc((size_t)N*16*4);
  u16* Sin16     = (u16*)alloc((size_t)N*64*2);
  u16* Sout16    = (u16*)alloc((size_t)N*64*2);
  u16* g0        = (u16*)alloc((size_t)N*64*2);        // fp16 h buffers
  u16* gA        = (u16*)alloc((size_t)N*64*2);
  u16* gB        = (u16*)alloc((size_t)N*64*2);
  u16* bA        = (u16*)alloc((size_t)R*80*64*8*2);
  u16* bB        = (u16*)alloc((size_t)R*96*64*8*2);
  u16* bC        = (u16*)alloc((size_t)32*64*8*2);
  float* partial = (float*)alloc((size_t)NB5*128*4);

  hipMemsetAsync(off, 0, ((size_t)2*N+1)*4, stream);

  int eb = (E + 255)/256;
  k_count<<<eb, 256, 0, stream>>>(uidx, vidx, off, rin, rout, N, E);
  int M = 2*N;
  int nb = (M + 255)/256;
  k_scan1<<<nb, 256, 0, stream>>>(off, part, M);
  k_scan2<<<1, 1024, 0, stream>>>(part, nb);
  k_scan3<<<nb, 256, 0, stream>>>(off, part, M, 2*E);
  k_fill2<<<eb, 256, 0, stream>>>(uidx, vidx, off, rin, rout, rows, srcs, N, E);
  int wb = (N + 3)/4;
  k_einout<<<wb, 256, 0, stream>>>(ev, off, rows, Ein, Eout, N);
  k_cvt16<<<(N*64 + 255)/256, 256, 0, stream>>>(nodev, g0, N*64);

  // one-time fp16 B-fragment builds (merged)
  k_pre<<<R*80 + R*96 + 32, 64, 0, stream>>>(Wef, bef, Wer, ber, Wih, Whh,
                                             bih, bhh, Wfm, Wgm, bA, bB, bC, R);

  int nT = (N + 63)/64;
  const u16* g16cur = g0;
  u16* gbufs[2] = {gA, gB};
  for(int r = 0; r < R; ++r){
    k_aggr<<<wb, 256, 0, stream>>>(g16cur, off, srcs, Sin16, Sout16, N);
    u16* gn = gbufs[r & 1];
    k34_mfma<<<nT, 512, 0, stream>>>(g16cur, Sin16, Sout16, Ein, Eout, off,
                                     bA + (size_t)r*80*64*8,
                                     bB + (size_t)r*96*64*8,
                                     gn, N);
    g16cur = gn;
  }
  k5m<<<NB5, 512, 0, stream>>>(g16cur, bC, bfm, bgm, partial, N, nT);
  k6_dec<<<1, 256, 0, stream>>>(partial, NB5, g16cur, Wdec, bdec, tgt, (float*)d_out);
}

// Round 20
// 418.664 us; speedup vs baseline: 1.1481x; 1.0001x over previous
//
#include <hip/hip_runtime.h>
#include <math.h>

#define D64 64
#define ES16 16
#define NB5 256

typedef unsigned short u16;
typedef _Float16 half8 __attribute__((ext_vector_type(8)));
typedef __attribute__((ext_vector_type(4))) float f32x4;

// fp16 MFMA pipeline — BEST CONFIG (round-16 measured 421us), all ledgers closed:
// k_count: plain-int atomics+ranks (67us; packed-u16 = 70 worse; atomic-op-rate
//   bound ~10/cyc device-wide).
// k_fill2: atomic-free scatter via precomputed ranks (plain 4B stores; int2 and
//   nontemporal variants both regressed).
// k_aggr: standalone, wave/node, half-wave/direction, fp16 gathers, 16/8/4/1
//   unroll (gather-request-rate bound; round-18 fusion into k34 regressed:
//   282us fused vs 210us separate — lost inter-node MLP + LDS conflicts).
// k34_mfma: fp16 MFMA, h16-only state (absmax 0.0 => ample headroom).

__device__ __forceinline__ float sigf(float x){ return 1.0f/(1.0f + __expf(-x)); }
__device__ __forceinline__ float tanhfast(float x){ return 2.0f*sigf(2.0f*x) - 1.0f; }
__device__ __forceinline__ u16 f2h(float f){             // RNE fp32->fp16
  _Float16 h = (_Float16)f;
  u16 r; __builtin_memcpy(&r, &h, 2); return r;
}
__device__ __forceinline__ float h2f(u16 b){
  _Float16 h; __builtin_memcpy(&h, &b, 2); return (float)h;
}
__device__ __forceinline__ float2 up2(unsigned w){       // u32 -> 2 floats
  _Float16 lo, hi;
  u16 a = (u16)(w & 0xFFFF), b = (u16)(w >> 16);
  __builtin_memcpy(&lo, &a, 2); __builtin_memcpy(&hi, &b, 2);
  return make_float2((float)lo, (float)hi);
}

// ---------------- CSR build ----------------
__global__ void k_count(const int* __restrict__ u, const int* __restrict__ v,
                        int* __restrict__ cnt, int* __restrict__ rin,
                        int* __restrict__ rout, int N, int E){
  int e = blockIdx.x*256 + threadIdx.x;
  if(e < E){
    rin[e]  = atomicAdd(&cnt[v[e]], 1);
    rout[e] = atomicAdd(&cnt[N + u[e]], 1);
  }
}

__global__ void k_scan1(const int* __restrict__ cnt, int* __restrict__ part, int M){
  __shared__ int sm[256];
  int i = blockIdx.x*256 + threadIdx.x;
  sm[threadIdx.x] = (i < M) ? cnt[i] : 0;
  __syncthreads();
  for(int s = 128; s > 0; s >>= 1){
    if(threadIdx.x < s) sm[threadIdx.x] += sm[threadIdx.x + s];
    __syncthreads();
  }
  if(threadIdx.x == 0) part[blockIdx.x] = sm[0];
}

__global__ void k_scan2(int* __restrict__ part, int nb){
  __shared__ int sm[1024];
  int t = threadIdx.x;
  int orig = (t < nb) ? part[t] : 0;
  sm[t] = orig;
  __syncthreads();
  for(int off = 1; off < 1024; off <<= 1){
    int add = (t >= off) ? sm[t - off] : 0;
    __syncthreads();
    sm[t] += add;
    __syncthreads();
  }
  if(t < nb) part[t] = sm[t] - orig;  // exclusive prefix
}

__global__ void k_scan3(int* __restrict__ cnt, const int* __restrict__ part,
                        int M, int total){
  __shared__ int sm[256];
  int t = threadIdx.x;
  int i = blockIdx.x*256 + t;
  int orig = (i < M) ? cnt[i] : 0;
  sm[t] = orig;
  __syncthreads();
  for(int off = 1; off < 256; off <<= 1){
    int add = (t >= off) ? sm[t - off] : 0;
    __syncthreads();
    sm[t] += add;
    __syncthreads();
  }
  if(i < M) cnt[i] = part[blockIdx.x] + sm[t] - orig;   // exclusive offset
  if(i == 0) cnt[M] = total;
}

// Atomic-free scatter: positions from off[] + precomputed ranks.
__global__ void k_fill2(const int* __restrict__ u, const int* __restrict__ v,
                        const int* __restrict__ off, const int* __restrict__ rin,
                        const int* __restrict__ rout, int* __restrict__ rows,
                        int* __restrict__ srcs, int N, int E){
  int e = blockIdx.x*256 + threadIdx.x;
  if(e < E){
    int uu = u[e], vv = v[e];
    int p = off[vv] + rin[e];
    int q = off[N + uu] + rout[e];
    rows[p] = e; srcs[p] = uu;
    rows[q] = e; srcs[q] = vv;
  }
}

// ---------------- fp32 -> fp16 h conversion (round 0 input) ----------------
__global__ void k_cvt16(const float* __restrict__ src, u16* __restrict__ dst, int total){
  int i = blockIdx.x*256 + threadIdx.x;
  if(i < total) dst[i] = f2h(src[i]);
}

// ---------------- round-constant edge-feature sums ----------------
__global__ void k_einout(const float* __restrict__ ev, const int* __restrict__ off,
                         const int* __restrict__ rows,
                         float* __restrict__ Ein, float* __restrict__ Eout, int N){
  int n = (blockIdx.x*blockDim.x + threadIdx.x) >> 6;
  int lane = threadIdx.x & 63;
  if(n >= N) return;
  int t = lane & 15, s = lane >> 4;
  {
    float a0 = 0.f, a1 = 0.f;
    int p = off[n] + s, p1 = off[n+1];
    for(; p + 4 < p1; p += 8){
      a0 += ev[rows[p]*ES16 + t];
      a1 += ev[rows[p+4]*ES16 + t];
    }
    if(p < p1) a0 += ev[rows[p]*ES16 + t];
    float a = a0 + a1;
    a += __shfl_xor(a, 16, 64);
    a += __shfl_xor(a, 32, 64);
    if(lane < 16) Ein[n*ES16 + lane] = a;
  }
  {
    float b0 = 0.f, b1 = 0.f;
    int p = off[N+n] + s, p1 = off[N+n+1];
    for(; p + 4 < p1; p += 8){
      b0 += ev[rows[p]*ES16 + t];
      b1 += ev[rows[p+4]*ES16 + t];
    }
    if(p < p1) b0 += ev[rows[p]*ES16 + t];
    float b = b0 + b1;
    b += __shfl_xor(b, 16, 64);
    b += __shfl_xor(b, 32, 64);
    if(lane < 16) Eout[n*ES16 + lane] = b;
  }
}

// ---------------- per-round sparse aggregation ----------------
// One wave per NODE; lanes 0..31 = in, lanes 32..63 = out. 16/8/4/1 unroll.
__global__ void k_aggr(const u16* __restrict__ h16, const int* __restrict__ off,
                       const int* __restrict__ srcs,
                       u16* __restrict__ Sin16, u16* __restrict__ Sout16, int N){
  int n = (blockIdx.x*blockDim.x + threadIdx.x) >> 6;
  int lane = threadIdx.x & 63;
  if(n >= N) return;
  const int half = lane >> 5;          // 0: Sin, 1: Sout
  const int fl   = lane & 31;          // feature-pair index
  const int gw   = half ? (N + n) : n;
  int p  = off[gw], p1 = off[gw+1];
  const unsigned* hsrc = (const unsigned*)h16;
  float sx0 = 0.f, sy0 = 0.f, sx1 = 0.f, sy1 = 0.f;
  for(; p + 16 <= p1; p += 16){
    int s[16]; unsigned w[16];
    #pragma unroll
    for(int j = 0; j < 16; ++j) s[j] = srcs[p + j];
    #pragma unroll
    for(int j = 0; j < 16; ++j) w[j] = hsrc[(size_t)s[j]*32 + fl];
    #pragma unroll
    for(int j = 0; j < 16; j += 4){
      float2 f0 = up2(w[j]), f1 = up2(w[j+1]), f2 = up2(w[j+2]), f3 = up2(w[j+3]);
      sx0 += f0.x + f1.x; sy0 += f0.y + f1.y;
      sx1 += f2.x + f3.x; sy1 += f2.y + f3.y;
    }
  }
  for(; p + 8 <= p1; p += 8){
    int s0 = srcs[p],   s1 = srcs[p+1], s2 = srcs[p+2], s3 = srcs[p+3];
    int s4 = srcs[p+4], s5 = srcs[p+5], s6 = srcs[p+6], s7 = srcs[p+7];
    unsigned w0 = hsrc[(size_t)s0*32 + fl];
    unsigned w1 = hsrc[(size_t)s1*32 + fl];
    unsigned w2 = hsrc[(size_t)s2*32 + fl];
    unsigned w3 = hsrc[(size_t)s3*32 + fl];
    unsigned w4 = hsrc[(size_t)s4*32 + fl];
    unsigned w5 = hsrc[(size_t)s5*32 + fl];
    unsigned w6 = hsrc[(size_t)s6*32 + fl];
    unsigned w7 = hsrc[(size_t)s7*32 + fl];
    float2 f0 = up2(w0), f1 = up2(w1), f2 = up2(w2), f3 = up2(w3);
    float2 f4 = up2(w4), f5 = up2(w5), f6 = up2(w6), f7 = up2(w7);
    sx0 += (f0.x + f1.x) + (f4.x + f5.x);
    sy0 += (f0.y + f1.y) + (f4.y + f5.y);
    sx1 += (f2.x + f3.x) + (f6.x + f7.x);
    sy1 += (f2.y + f3.y) + (f6.y + f7.y);
  }
  for(; p + 4 <= p1; p += 4){
    int s0 = srcs[p], s1 = srcs[p+1], s2 = srcs[p+2], s3 = srcs[p+3];
    unsigned w0 = hsrc[(size_t)s0*32 + fl];
    unsigned w1 = hsrc[(size_t)s1*32 + fl];
    unsigned w2 = hsrc[(size_t)s2*32 + fl];
    unsigned w3 = hsrc[(size_t)s3*32 + fl];
    float2 f0 = up2(w0), f1 = up2(w1), f2 = up2(w2), f3 = up2(w3);
    sx0 += f0.x + f1.x; sy0 += f0.y + f1.y;
    sx1 += f2.x + f3.x; sy1 += f2.y + f3.y;
  }
  for(; p < p1; ++p){
    float2 f0 = up2(hsrc[(size_t)srcs[p]*32 + fl]);
    sx0 += f0.x; sy0 += f0.y;
  }
  unsigned pw = (unsigned)f2h(sx0 + sx1) | ((unsigned)f2h(sy0 + sy1) << 16);
  unsigned* dst = half ? (unsigned*)Sout16 : (unsigned*)Sin16;
  dst[(size_t)n*32 + fl] = pw;
}

// ---------------- merged weight -> fp16 B-fragment preprocess ----------------
__global__ void k_pre(const float* __restrict__ Wef, const float* __restrict__ bef,
                      const float* __restrict__ Wer, const float* __restrict__ ber,
                      const float* __restrict__ Wih, const float* __restrict__ Whh,
                      const float* __restrict__ bih, const float* __restrict__ bhh,
                      const float* __restrict__ Wfm, const float* __restrict__ Wgm,
                      u16* __restrict__ bA, u16* __restrict__ bB,
                      u16* __restrict__ bC, int R){
  int b = blockIdx.x;
  int lane = threadIdx.x;
  u16 val8[8];
  u16* dst;
  if(b < R*80){
    int r = b / 80, t = b % 80;
    int nt = t / 10, kt = t % 10;
    int j = nt*16 + (lane & 15);
    int ks0 = kt*32 + (lane >> 4)*8;
    const float* wef = Wef + (size_t)r*128*144;
    const float* wer = Wer + (size_t)r*128*144;
    #pragma unroll
    for(int e = 0; e < 8; ++e){
      int ks = ks0 + e;
      float val;
      if(ks < 144)       val = wef[j*144 + ks];
      else if(ks == 144) val = bef[r*128 + j];
      else if(ks < 160)  val = 0.f;
      else if(ks < 304)  val = wer[j*144 + (ks - 160)];
      else if(ks == 304) val = ber[r*128 + j];
      else               val = 0.f;
      val8[e] = f2h(val);
    }
    dst = bA + ((size_t)b*64 + lane)*8;
  } else if(b < R*80 + R*96){
    int bb = b - R*80;
    int r = bb / 96, t = bb % 96;
    int nt = t / 8, kt = t % 8;
    int q = nt*16 + (lane & 15);
    int ks0 = kt*32 + (lane >> 4)*8;
    const float* wih = Wih + (size_t)r*192*128;
    const float* whh = Whh + (size_t)r*192*64;
    #pragma unroll
    for(int e = 0; e < 8; ++e){
      int ks = ks0 + e;
      float val;
      if(ks < 128)       val = wih[q*128 + ks];
      else if(ks == 128) val = bih[r*192 + q];
      else if(ks < 160)  val = 0.f;
      else if(ks < 224)  val = whh[q*64 + (ks - 160)];
      else if(ks == 224) val = bhh[r*192 + q];
      else               val = 0.f;
      val8[e] = f2h(val);
    }
    dst = bB + ((size_t)bb*64 + lane)*8;
  } else {
    int bb = b - R*80 - R*96;
    int nt = bb >> 2, kt = (bb >> 1) & 1, fg = bb & 1;
    int j = nt*16 + (lane & 15);
    int ks0 = kt*32 + (lane >> 4)*8;
    const float* W = fg ? Wgm : Wfm;
    #pragma unroll
    for(int e = 0; e < 8; ++e) val8[e] = f2h(W[j*64 + ks0 + e]);
    dst = bC + ((size_t)bb*64 + lane)*8;
  }
  #pragma unroll
  for(int e = 0; e < 8; ++e) dst[e] = val8[e];
}

// ---------------- fused node transform + GRU via MFMA (fp16, h16-only) ------
__global__ __launch_bounds__(512) void k34_mfma(
    const u16* __restrict__ h16, const u16* __restrict__ Sin16,
    const u16* __restrict__ Sout16, const float* __restrict__ Ein,
    const float* __restrict__ Eout, const int* __restrict__ off,
    const u16* __restrict__ bA, const u16* __restrict__ bB,
    u16* __restrict__ h16next, int N){
  __shared__ u16 xA[64][328];   // 320 + pad
  __shared__ u16 x2[64][264];   // 256 + pad
  const int lane = threadIdx.x & 63;
  const int wv   = __builtin_amdgcn_readfirstlane(threadIdx.x >> 6);
  const int base = blockIdx.x * 64;

  // ---- staging (all-fp16 inputs) ----
  for(int ii = 0; ii < 8; ++ii){
    int i = wv*8 + ii;
    int n = base + i; if(n >= N) n = N - 1;
    float fi = (float)(off[n+1] - off[n]);
    float fo = (float)(off[N+n+1] - off[N+n]);
    u16 hv16 = h16[(size_t)n*D64 + lane];
    float hv = h2f(hv16);
    xA[i][lane]        = Sin16[(size_t)n*D64 + lane];
    xA[i][64 + lane]   = f2h(fi*hv);
    xA[i][160 + lane]  = f2h(fo*hv);
    xA[i][224 + lane]  = Sout16[(size_t)n*D64 + lane];
    x2[i][160 + lane]  = hv16;
    if(lane < 16){
      xA[i][128 + lane] = f2h(Ein[(size_t)n*ES16 + lane]);
      xA[i][288 + lane] = f2h(Eout[(size_t)n*ES16 + lane]);
    }
    if(lane == 0){
      xA[i][144] = f2h(fi); xA[i][304] = f2h(fo);
      x2[i][128] = 0x3C00;  x2[i][224] = 0x3C00;   // fp16 1.0
    }
    if(lane >= 1 && lane < 16){ xA[i][144 + lane] = 0; xA[i][304 + lane] = 0; }
    if(lane >= 1 && lane < 32){ x2[i][128 + lane] = 0; x2[i][224 + lane] = 0; }
  }
  __syncthreads();

  // ---- phase A: agg = x @ B_A^T ; wave n-tile = wv ----
  half8 bw[10];
  #pragma unroll
  for(int kt = 0; kt < 10; ++kt)
    bw[kt] = *(const half8*)(bA + ((size_t)(wv*10 + kt)*64 + lane)*8);

  f32x4 accA[4];
  const int arow = lane & 15;
  const int akof = (lane >> 4) * 8;
  #pragma unroll
  for(int m = 0; m < 4; ++m){
    f32x4 a = {0.f, 0.f, 0.f, 0.f};
    #pragma unroll
    for(int kt = 0; kt < 10; ++kt){
      half8 av = *(const half8*)&xA[m*16 + arow][kt*32 + akof];
      a = __builtin_amdgcn_mfma_f32_16x16x32_f16(av, bw[kt], a, 0, 0, 0);
    }
    accA[m] = a;
  }

  // ---- agg (fp16) -> x2[:, jb..jb+15]; C/D: col=lane&15, row=(lane>>4)*4+reg ----
  const int jb = wv * 16;
  #pragma unroll
  for(int m = 0; m < 4; ++m){
    #pragma unroll
    for(int reg = 0; reg < 4; ++reg){
      int nl = m*16 + (lane >> 4)*4 + reg;
      x2[nl][jb + (lane & 15)] = f2h(accA[m][reg]);
    }
  }
  __syncthreads();

  // ---- phase B: gates = x2 @ B_B^T ; 2 units/wave ----
  #pragma unroll
  for(int uu = 0; uu < 2; ++uu){
    const int unit = wv*2 + uu;
    const int mt  = unit >> 2;
    const int tri = unit & 3;
    f32x4 aR  = {0.f,0.f,0.f,0.f};
    f32x4 aZ  = {0.f,0.f,0.f,0.f};
    f32x4 aNi = {0.f,0.f,0.f,0.f};
    f32x4 aNh = {0.f,0.f,0.f,0.f};
    #pragma unroll
    for(int kt = 0; kt < 8; ++kt){
      half8 av = *(const half8*)&x2[mt*16 + arow][kt*32 + akof];
      half8 bR = *(const half8*)(bB + ((size_t)((tri    )*8 + kt)*64 + lane)*8);
      half8 bZ = *(const half8*)(bB + ((size_t)((tri + 4)*8 + kt)*64 + lane)*8);
      half8 bN = *(const half8*)(bB + ((size_t)((tri + 8)*8 + kt)*64 + lane)*8);
      aR = __builtin_amdgcn_mfma_f32_16x16x32_f16(av, bR, aR, 0, 0, 0);
      aZ = __builtin_amdgcn_mfma_f32_16x16x32_f16(av, bZ, aZ, 0, 0, 0);
      if(kt < 5) aNi = __builtin_amdgcn_mfma_f32_16x16x32_f16(av, bN, aNi, 0, 0, 0);
      else       aNh = __builtin_amdgcn_mfma_f32_16x16x32_f16(av, bN, aNh, 0, 0, 0);
    }
    const int q = tri*16 + (lane & 15);
    #pragma unroll
    for(int reg = 0; reg < 4; ++reg){
      int node = base + mt*16 + (lane >> 4)*4 + reg;
      float r  = sigf(aR[reg]);
      float z  = sigf(aZ[reg]);
      float nn = tanhfast(aNi[reg] + r*aNh[reg]);
      if(node < N){
        float hq = h2f(h16[(size_t)node*D64 + q]);
        h16next[(size_t)node*D64 + q] = f2h((1.f - z)*nn + z*hq);
      }
    }
  }
}

// ---------------- gated readout via MFMA ----------------
__global__ __launch_bounds__(512) void k5m(
    const u16* __restrict__ h16, const u16* __restrict__ bC,
    const float* __restrict__ bfm, const float* __restrict__ bgm,
    float* __restrict__ partials, int N, int nT){
  __shared__ u16 xh[64][72];   // 64 fp16 + pad -> 144B stride (9*16)
  const int lane = threadIdx.x & 63;
  const int wv   = __builtin_amdgcn_readfirstlane(threadIdx.x >> 6);
  const int arow = lane & 15;
  const int akof = (lane >> 4) * 8;
  half8 bF[2], bG[2];
  #pragma unroll
  for(int kt = 0; kt < 2; ++kt){
    bF[kt] = *(const half8*)(bC + ((size_t)(wv*4 + kt*2 + 0)*64 + lane)*8);
    bG[kt] = *(const half8*)(bC + ((size_t)(wv*4 + kt*2 + 1)*64 + lane)*8);
  }
  const float fb = bfm[wv*16 + arow];
  const float gb = bgm[wv*16 + arow];
  float acc = 0.f;
  for(int tile = blockIdx.x; tile < nT; tile += NB5){
    const int base = tile * 64;
    __syncthreads();
    for(int ii = 0; ii < 8; ++ii){
      int i = wv*8 + ii;
      int n = base + i;
      xh[i][lane] = (n < N) ? h16[(size_t)n*D64 + lane] : (u16)0;
    }
    __syncthreads();
    #pragma unroll
    for(int m = 0; m < 4; ++m){
      f32x4 F = {0.f,0.f,0.f,0.f};
      f32x4 G = {0.f,0.f,0.f,0.f};
      #pragma unroll
      for(int kt = 0; kt < 2; ++kt){
        half8 av = *(const half8*)&xh[m*16 + arow][kt*32 + akof];
        F = __builtin_amdgcn_mfma_f32_16x16x32_f16(av, bF[kt], F, 0, 0, 0);
        G = __builtin_amdgcn_mfma_f32_16x16x32_f16(av, bG[kt], G, 0, 0, 0);
      }
      #pragma unroll
      for(int reg = 0; reg < 4; ++reg){
        int node = base + m*16 + (lane >> 4)*4 + reg;
        if(node < N)
          acc += (F[reg] + fb) * sigf(G[reg] + gb);
      }
    }
  }
  acc += __shfl_xor(acc, 16, 64);
  acc += __shfl_xor(acc, 32, 64);
  if(lane < 16) partials[blockIdx.x*128 + wv*16 + lane] = acc;
}

__global__ void k6_dec(const float* __restrict__ partials, int nb,
                       const u16* __restrict__ h16,
                       const float* __restrict__ Wdec, const float* __restrict__ bdec,
                       const int* __restrict__ tgt, float* __restrict__ out){
  __shared__ float sm[256];
  int t = threadIdx.x;
  float v = 0.f;
  if(t < 128){
    float s0 = 0.f, s1 = 0.f, s2 = 0.f, s3 = 0.f;
    for(int b = 0; b + 4 <= nb; b += 4){
      s0 += partials[(b+0)*128 + t];
      s1 += partials[(b+1)*128 + t];
      s2 += partials[(b+2)*128 + t];
      s3 += partials[(b+3)*128 + t];
    }
    v = ((s0 + s1) + (s2 + s3)) * Wdec[t];
  } else if(t < 192){
    v = h2f(h16[(size_t)tgt[0]*D64 + (t - 128)]) * Wdec[t];
  }
  sm[t] = v;
  __syncthreads();
  for(int s = 128; s > 0; s >>= 1){
    if(t < s) sm[t] += sm[t + s];
    __syncthreads();
  }
  if(t == 0) out[0] = sm[0] + bdec[0];
}

extern "C" void kernel_launch(void* const* d_in, const int* in_sizes, int n_in,
                              void* d_out, int out_size, void* d_ws, size_t ws_size,
                              hipStream_t stream){
  const float* nodev = (const float*)d_in[0];
  const float* ev    = (const float*)d_in[1];
  const float* Wef   = (const float*)d_in[2];
  const float* bef   = (const float*)d_in[3];
  const float* Wer   = (const float*)d_in[4];
  const float* ber   = (const float*)d_in[5];
  const float* Wih   = (const float*)d_in[6];
  const float* Whh   = (const float*)d_in[7];
  const float* bih   = (const float*)d_in[8];
  const float* bhh   = (const float*)d_in[9];
  const float* Wfm   = (const float*)d_in[10];
  const float* bfm   = (const float*)d_in[11];
  const float* Wgm   = (const float*)d_in[12];
  const float* bgm   = (const float*)d_in[13];
  const float* Wdec  = (const float*)d_in[14];
  const float* bdec  = (const float*)d_in[15];
  const int* uidx    = (const int*)d_in[16];
  const int* vidx    = (const int*)d_in[17];
  const int* tgt     = (const int*)d_in[18];

  const int N = in_sizes[0] / 64;
  const int E = in_sizes[16];
  const int R = in_sizes[2] / (128*144);

  char* w = (char*)d_ws;
  auto alloc = [&](size_t bytes) -> void* {
    void* p = (void*)w;
    w += (bytes + 255) & ~(size_t)255;
    return p;
  };
  int* off       = (int*)alloc(((size_t)2*N + 1) * 4);
  int* rin       = (int*)alloc((size_t)E * 4);
  int* rout      = (int*)alloc((size_t)E * 4);
  int* rows      = (int*)alloc((size_t)2*E * 4);
  int* srcs      = (int*)alloc((size_t)2*E * 4);
  int* part      = (int*)alloc(4096 * 4);
  float* Ein     = (float*)alloc((size_t)N*16*4);
  float* Eout    = (float*)alloc((size_t)N*16*4);
  u16* Sin16     = (u16*)alloc((size_t)N*64*2);
  u16* Sout16    = (u16*)alloc((size_t)N*64*2);
  u16* g0        = (u16*)alloc((size_t)N*64*2);        // fp16 h buffers
  u16* gA        = (u16*)alloc((size_t)N*64*2);
  u16* gB        = (u16*)alloc((size_t)N*64*2);
  u16* bA        = (u16*)alloc((size_t)R*80*64*8*2);
  u16* bB        = (u16*)alloc((size_t)R*96*64*8*2);
  u16* bC        = (u16*)alloc((size_t)32*64*8*2);
  float* partial = (float*)alloc((size_t)NB5*128*4);

  hipMemsetAsync(off, 0, ((size_t)2*N+1)*4, stream);

  int eb = (E + 255)/256;
  k_count<<<eb, 256, 0, stream>>>(uidx, vidx, off, rin, rout, N, E);
  int M = 2*N;
  int nb = (M + 255)/256;
  k_scan1<<<nb, 256, 0, stream>>>(off, part, M);
  k_scan2<<<1, 1024, 0, stream>>>(part, nb);
  k_scan3<<<nb, 256, 0, stream>>>(off, part, M, 2*E);
  k_fill2<<<eb, 256, 0, stream>>>(uidx, vidx, off, rin, rout, rows, srcs, N, E);
  int wb = (N + 3)/4;
  k_einout<<<wb, 256, 0, stream>>>(ev, off, rows, Ein, Eout, N);
  k_cvt16<<<(N*64 + 255)/256, 256, 0, stream>>>(nodev, g0, N*64);

  // one-time fp16 B-fragment builds (merged)
  k_pre<<<R*80 + R*96 + 32, 64, 0, stream>>>(Wef, bef, Wer, ber, Wih, Whh,
                                             bih, bhh, Wfm, Wgm, bA, bB, bC, R);

  int nT = (N + 63)/64;
  const u16* g16cur = g0;
  u16* gbufs[2] = {gA, gB};
  for(int r = 0; r < R; ++r){
    k_aggr<<<wb, 256, 0, stream>>>(g16cur, off, srcs, Sin16, Sout16, N);
    u16* gn = gbufs[r & 1];
    k34_mfma<<<nT, 512, 0, stream>>>(g16cur, Sin16, Sout16, Ein, Eout, off,
                                     bA + (size_t)r*80*64*8,
                                     bB + (size_t)r*96*64*8,
                                     gn, N);
    g16cur = gn;
  }
  k5m<<<NB5, 512, 0, stream>>>(g16cur, bC, bfm, bgm, partial, N, nT);
  k6_dec<<<1, 256, 0, stream>>>(partial, NB5, g16cur, Wdec, bdec, tgt, (float*)d_out);
}